// Round 5
// baseline (171.111 us; speedup 1.0000x reference)
//
#include <hip/hip_runtime.h>
#include <hip/hip_bf16.h>
#include <stdint.h>

#define NN 8192
#define FIN 512
#define FOUT 64
#define ALPHA 0.2f
#define TJ 256
#define NT (NN / TJ)     // 32
#define RB 32            // rows per attn block
#define NBLK (NN / RB)   // 256

typedef float f32x4 __attribute__((ext_vector_type(4)));
typedef int   i32x4 __attribute__((ext_vector_type(4)));
typedef short bf16x8 __attribute__((ext_vector_type(8)));

__device__ __forceinline__ unsigned packbits(i32x4 a, i32x4 b) {
  unsigned r = 0;
#pragma unroll
  for (int e = 0; e < 4; ++e) r |= (a[e] > 0 ? 1u : 0u) << e;
#pragma unroll
  for (int e = 0; e < 4; ++e) r |= (b[e] > 0 ? 1u : 0u) << (4 + e);
  return r;
}

// ---------- Fused stream kernel: bid<8192 -> adj->bits compact; else prep GEMM ----------
__global__ __launch_bounds__(256) void stream_kernel(
    const int* __restrict__ adj, const float* __restrict__ x,
    const float* __restrict__ W, const float* __restrict__ a,
    unsigned char* __restrict__ bits, unsigned short* __restrict__ bpack,
    float* __restrict__ er, float* __restrict__ rr,
    float* __restrict__ e2p, float* __restrict__ e2n) {
  const int lane = threadIdx.x & 63;
  const int bid = blockIdx.x;

  if (bid < 8192) {
    // ---- compact: wave handles 2048 consecutive ints ----
    const int wid = bid * 4 + (threadIdx.x >> 6);
    const int* p0 = adj + (size_t)wid * 2048 + lane * 8;

    i32x4 va0 = *(const i32x4*)(p0);
    i32x4 vb0 = *(const i32x4*)(p0 + 4);
    i32x4 va1 = *(const i32x4*)(p0 + 512);
    i32x4 vb1 = *(const i32x4*)(p0 + 516);
    i32x4 va2 = *(const i32x4*)(p0 + 1024);
    i32x4 vb2 = *(const i32x4*)(p0 + 1028);
    i32x4 va3 = *(const i32x4*)(p0 + 1536);
    i32x4 vb3 = *(const i32x4*)(p0 + 1540);

    unsigned char* ob = bits + (size_t)wid * 256 + lane;
    ob[0]   = (unsigned char)packbits(va0, vb0);
    ob[64]  = (unsigned char)packbits(va1, vb1);
    ob[128] = (unsigned char)packbits(va2, vb2);
    ob[192] = (unsigned char)packbits(va3, vb3);
    return;
  }

  // ---- prep: h = x@W, tables er/rr (rows), e2p/e2n (cols), bpack (B-frag layout) ----
  const int g = (bid - 8192) * 4 + (threadIdx.x >> 6);  // 0..1023
  const int i0 = g * 8;

  float acc[8];
#pragma unroll
  for (int r = 0; r < 8; ++r) acc[r] = 0.0f;

  for (int k = 0; k < FIN; k += 4) {
    float w0 = W[(k + 0) * FOUT + lane];
    float w1 = W[(k + 1) * FOUT + lane];
    float w2 = W[(k + 2) * FOUT + lane];
    float w3 = W[(k + 3) * FOUT + lane];
#pragma unroll
    for (int r = 0; r < 8; ++r) {
      f32x4 xv = *(const f32x4*)(x + (size_t)(i0 + r) * FIN + k);
      acc[r] = fmaf(xv[0], w0, acc[r]);
      acc[r] = fmaf(xv[1], w1, acc[r]);
      acc[r] = fmaf(xv[2], w2, acc[r]);
      acc[r] = fmaf(xv[3], w3, acc[r]);
    }
  }

  const float a1c = a[lane];
  const float a2c = a[FOUT + lane];
#pragma unroll
  for (int r = 0; r < 8; ++r) {
    float p1 = acc[r] * a1c;
    float p2 = acc[r] * a2c;
#pragma unroll
    for (int off = 32; off >= 1; off >>= 1) {
      p1 += __shfl_xor(p1, off, 64);
      p2 += __shfl_xor(p2, off, 64);
    }
    if (lane == 0) {
      er[i0 + r] = __expf(-p1);
      rr[i0 + r] = __expf(-0.8f * p1);
      e2p[i0 + r] = __expf(p2);
      e2n[i0 + r] = __expf(ALPHA * p2);
    }
  }

  unsigned short hs[8];
#pragma unroll
  for (int r = 0; r < 8; ++r) {
    __hip_bfloat16 hb = __float2bfloat16(acc[r]);
    hs[r] = *reinterpret_cast<unsigned short*>(&hb);
  }
  const int jb = i0 >> 5;
  const int kg = (i0 >> 3) & 3;
  const int cb = lane >> 4;
  const int rrr = lane & 15;
  *(uint4*)(bpack + ((size_t)jb * 2048 + cb * 512 + kg * 128 + rrr * 8)) = *(uint4*)hs;
}

// ---------- attn: 256 blocks x 32 rows, 8 waves; raw barrier, no vmcnt drain ----------
__global__ __launch_bounds__(512, 2) void attn_kernel(
    const unsigned char* __restrict__ bits, const unsigned short* __restrict__ bpack,
    const float* __restrict__ er, const float* __restrict__ rr,
    const float* __restrict__ e2p, const float* __restrict__ e2n,
    float* __restrict__ out) {
  // LDS map: pw dbuf [0,32K) (16KB each, row stride 512B, ^((row&7)<<4));
  // e2 dbuf [32K,36K) (2KB each: e2p@+0, e2n@+1024, ^(((b>>8)&7)<<4));
  // num alias [0,64K) = [8][32][64] f32; den @65536 (32 f32)
  __shared__ __align__(16) char lds[65536 + 128];

  const int tid = threadIdx.x;
  const int lane = tid & 63;
  const int wv = tid >> 6;       // 0..7
  const int rg = blockIdx.x;     // 0..255
  const int r15 = lane & 15;
  const int kgrp = lane >> 4;
  const int jl = r15;            // weight-role j-slice
  const int qr = kgrp;           // weight-role row quarter

  const int wrow = wv * 4 + qr;          // 0..31
  const int growr = rg * RB + wrow;
  const float er_v = er[growr];
  const float rr_v = rr[growr];
  const unsigned char* brow = bits + (size_t)growr * (NN / 8);

  f32x4 acc00 = {0.f,0.f,0.f,0.f}, acc01 = acc00, acc02 = acc00, acc03 = acc00;
  f32x4 acc10 = acc00, acc11 = acc00, acc12 = acc00, acc13 = acc00;
  float den = 0.0f;

  bf16x8 bA[4], bB[4];
  unsigned mb;

  // ---- prologue: stage e2 tile 0, load B(0), bits(0) ----
  {
    char* eb = lds + 32768;   // buf 0
    if (tid < 256) {
      float v = e2p[tid];
      int b = tid * 4; b ^= ((b >> 8) & 7) << 4;
      *(float*)(eb + b) = v;
    } else {
      const int q_ = tid - 256;
      float v = e2n[q_];
      int b = q_ * 4; b ^= ((b >> 8) & 7) << 4;
      *(float*)(eb + 1024 + b) = v;
    }
    const unsigned short* bp = bpack + ((size_t)(wv) * 2048) + lane * 8;
    bA[0] = *(const bf16x8*)(bp);        bA[1] = *(const bf16x8*)(bp + 512);
    bA[2] = *(const bf16x8*)(bp + 1024); bA[3] = *(const bf16x8*)(bp + 1536);
    mb = *(const unsigned short*)(brow + jl * 2);
  }
  asm volatile("s_waitcnt lgkmcnt(0)\n\ts_barrier" ::: "memory");

#define ATTN_ITER(T_, BC, BN) do { \
    const int t_ = (T_); \
    const int tn_ = (t_ + 1) & (NT - 1); \
    { /* stage e2 tile t+1 into buf (t+1)&1 */ \
      char* eb = lds + 32768 + ((t_ + 1) & 1) * 2048; \
      const int jt = tn_ * TJ; \
      if (tid < 256) { \
        float v = e2p[jt + tid]; \
        int b = tid * 4; b ^= ((b >> 8) & 7) << 4; \
        *(float*)(eb + b) = v; \
      } else { \
        const int q_ = tid - 256; \
        float v = e2n[jt + q_]; \
        int b = q_ * 4; b ^= ((b >> 8) & 7) << 4; \
        *(float*)(eb + 1024 + b) = v; \
      } \
    } \
    { /* prefetch B(t+1): stays in flight across the raw barrier */ \
      const unsigned short* bp = bpack + ((size_t)(tn_ * 8 + wv) * 2048) + lane * 8; \
      BN[0] = *(const bf16x8*)(bp);        BN[1] = *(const bf16x8*)(bp + 512); \
      BN[2] = *(const bf16x8*)(bp + 1024); BN[3] = *(const bf16x8*)(bp + 1536); \
    } \
    const unsigned mbn_ = *(const unsigned short*)(brow + tn_ * 32 + jl * 2); \
    { /* weights(t): rows wv*4+qr, j = t*256 + jl*16 .. +15 */ \
      char* eb = lds + 32768 + (t_ & 1) * 2048; \
      f32x4 ep[4], en[4]; \
      _Pragma("unroll") \
      for (int h = 0; h < 4; ++h) { \
        int b = jl * 64 + h * 16; b ^= ((b >> 8) & 7) << 4; \
        ep[h] = *(f32x4*)(eb + b); \
        en[h] = *(f32x4*)(eb + 1024 + b); \
      } \
      unsigned short w8[16]; \
      _Pragma("unroll") \
      for (int h = 0; h < 4; ++h) { \
        _Pragma("unroll") \
        for (int e = 0; e < 4; ++e) { \
          const int k = h * 4 + e; \
          float p = ep[h][e]; \
          float w = (p > er_v) ? p : rr_v * en[h][e]; \
          w = ((mb >> k) & 1u) ? w : 0.0f; \
          den += w; \
          __hip_bfloat16 hb = __float2bfloat16(w); \
          w8[k] = *reinterpret_cast<unsigned short*>(&hb); \
        } \
      } \
      char* pwb = lds + (t_ & 1) * 16384; \
      const int b0 = wrow * 512 + jl * 32; \
      *(uint4*)(pwb + (b0 ^ ((wrow & 7) << 4))) = *(uint4*)&w8[0]; \
      *(uint4*)(pwb + ((b0 + 16) ^ ((wrow & 7) << 4))) = *(uint4*)&w8[8]; \
    } \
    asm volatile("s_waitcnt lgkmcnt(0)\n\ts_barrier" ::: "memory"); \
    { /* MFMA(t): wave = k-slice wv (K=32), rows 0-15 and 16-31 */ \
      char* pwb = lds + (t_ & 1) * 16384; \
      const int bA0 = (r15 * 512 + wv * 64 + kgrp * 16) ^ ((r15 & 7) << 4); \
      const int bA1 = ((16 + r15) * 512 + wv * 64 + kgrp * 16) ^ ((r15 & 7) << 4); \
      bf16x8 A0 = *(bf16x8*)(pwb + bA0); \
      bf16x8 A1 = *(bf16x8*)(pwb + bA1); \
      acc00 = __builtin_amdgcn_mfma_f32_16x16x32_bf16(A0, BC[0], acc00, 0, 0, 0); \
      acc01 = __builtin_amdgcn_mfma_f32_16x16x32_bf16(A0, BC[1], acc01, 0, 0, 0); \
      acc02 = __builtin_amdgcn_mfma_f32_16x16x32_bf16(A0, BC[2], acc02, 0, 0, 0); \
      acc03 = __builtin_amdgcn_mfma_f32_16x16x32_bf16(A0, BC[3], acc03, 0, 0, 0); \
      acc10 = __builtin_amdgcn_mfma_f32_16x16x32_bf16(A1, BC[0], acc10, 0, 0, 0); \
      acc11 = __builtin_amdgcn_mfma_f32_16x16x32_bf16(A1, BC[1], acc11, 0, 0, 0); \
      acc12 = __builtin_amdgcn_mfma_f32_16x16x32_bf16(A1, BC[2], acc12, 0, 0, 0); \
      acc13 = __builtin_amdgcn_mfma_f32_16x16x32_bf16(A1, BC[3], acc13, 0, 0, 0); \
    } \
    mb = mbn_; \
  } while (0)

  for (int tt = 0; tt < NT; tt += 2) {
    ATTN_ITER(tt, bA, bB);
    ATTN_ITER(tt + 1, bB, bA);
  }
#undef ATTN_ITER

  // den: reduce across the 16 j-lanes of each row quarter
#pragma unroll
  for (int off = 1; off <= 8; off <<= 1) den += __shfl_xor(den, off, 64);
  float* dptr = (float*)(lds + 65536);
  if (jl == 0) dptr[wrow] = den;

  // all pw reads done before aliasing lds as num
  asm volatile("s_waitcnt lgkmcnt(0)\n\ts_barrier" ::: "memory");

  // num[ks=wv][row 32][col 64]; C layout: col = r15, row = kgrp*4 + reg
  float* nump = (float*)lds;
#pragma unroll
  for (int r = 0; r < 4; ++r) {
    const int rl0 = kgrp * 4 + r;
    nump[(wv * 32 + rl0) * 64 +  0 + r15] = acc00[r];
    nump[(wv * 32 + rl0) * 64 + 16 + r15] = acc01[r];
    nump[(wv * 32 + rl0) * 64 + 32 + r15] = acc02[r];
    nump[(wv * 32 + rl0) * 64 + 48 + r15] = acc03[r];
    const int rl1 = 16 + rl0;
    nump[(wv * 32 + rl1) * 64 +  0 + r15] = acc10[r];
    nump[(wv * 32 + rl1) * 64 + 16 + r15] = acc11[r];
    nump[(wv * 32 + rl1) * 64 + 32 + r15] = acc12[r];
    nump[(wv * 32 + rl1) * 64 + 48 + r15] = acc13[r];
  }
  asm volatile("s_waitcnt lgkmcnt(0)\n\ts_barrier" ::: "memory");

  // combine 8 k-slices, divide, elu, store (4 elems/thread)
#pragma unroll
  for (int p = 0; p < 4; ++p) {
    const int idx = tid + p * 512;
    const int orow = idx >> 6;
    const int ocol = idx & 63;
    float s = 0.0f;
#pragma unroll
    for (int k = 0; k < 8; ++k) s += nump[k * 2048 + orow * 64 + ocol];
    float v = s / dptr[orow];
    out[(size_t)(rg * RB + orow) * FOUT + ocol] = (v > 0.0f) ? v : (__expf(v) - 1.0f);
  }
}

extern "C" void kernel_launch(void* const* d_in, const int* in_sizes, int n_in,
                              void* d_out, int out_size, void* d_ws, size_t ws_size,
                              hipStream_t stream) {
  const float* x = (const float*)d_in[0];
  const int* adj = (const int*)d_in[1];
  const float* W = (const float*)d_in[2];
  const float* a = (const float*)d_in[3];
  float* out = (float*)d_out;

  char* ws = (char*)d_ws;
  unsigned short* bpack = (unsigned short*)ws;            // 1 MB
  float* er  = (float*)(ws + 0x100000);                   // 32 KB
  float* rr  = (float*)(ws + 0x108000);                   // 32 KB
  float* e2p = (float*)(ws + 0x110000);                   // 32 KB
  float* e2n = (float*)(ws + 0x118000);                   // 32 KB
  unsigned char* bits = (unsigned char*)(ws + 0x200000);  // 8 MB

  hipLaunchKernelGGL(stream_kernel, dim3(8192 + 256), dim3(256), 0, stream,
                     adj, x, W, a, bits, bpack, er, rr, e2p, e2n);
  hipLaunchKernelGGL(attn_kernel, dim3(NBLK), dim3(512), 0, stream,
                     bits, bpack, er, rr, e2p, e2n, out);
}

// Round 6
// 132.660 us; speedup vs baseline: 1.2899x; 1.2899x over previous
//
#include <hip/hip_runtime.h>
#include <stdint.h>

#define NN 8192
#define FIN 512
#define FOUT 64
#define ALPHA 0.2f
#define TJ 512
#define NT (NN / TJ)   // 16 tiles

typedef float f32x4 __attribute__((ext_vector_type(4)));
typedef int   i32x4 __attribute__((ext_vector_type(4)));
typedef short bf16x8 __attribute__((ext_vector_type(8)));

__device__ __forceinline__ unsigned short f2bf(float f) {
  union { float f; unsigned u; } v; v.f = f;
  unsigned r = (v.u + 0x7fffu + ((v.u >> 16) & 1u)) >> 16;
  return (unsigned short)r;
}

// ---------------- Phase 0: adj (int32) -> bitmask; persistent waves + NT loads -------------
__device__ __forceinline__ unsigned packbits(i32x4 a, i32x4 b) {
  unsigned r = 0;
#pragma unroll
  for (int e = 0; e < 4; ++e) r |= (a[e] > 0 ? 1u : 0u) << e;
#pragma unroll
  for (int e = 0; e < 4; ++e) r |= (b[e] > 0 ? 1u : 0u) << (4 + e);
  return r;
}

// 2048 blocks x 256 threads = 8192 waves, all resident (8 blocks/CU). Each wave streams
// 4 consecutive 2048-int chunks (32 KB contiguous). NT loads bypass L3 (no alloc/evict churn).
__global__ __launch_bounds__(256) void compact_kernel(
    const int* __restrict__ adj, unsigned char* __restrict__ bits) {
  const int lane = threadIdx.x & 63;
  const int g = blockIdx.x * 4 + (threadIdx.x >> 6);   // wave id 0..8191

#pragma unroll 1
  for (int it = 0; it < 4; ++it) {
    const int c = g * 4 + it;                          // chunk id 0..32767
    const int* p0 = adj + (size_t)c * 2048 + lane * 8;

    i32x4 va0 = __builtin_nontemporal_load((const i32x4*)(p0));
    i32x4 vb0 = __builtin_nontemporal_load((const i32x4*)(p0 + 4));
    i32x4 va1 = __builtin_nontemporal_load((const i32x4*)(p0 + 512));
    i32x4 vb1 = __builtin_nontemporal_load((const i32x4*)(p0 + 516));
    i32x4 va2 = __builtin_nontemporal_load((const i32x4*)(p0 + 1024));
    i32x4 vb2 = __builtin_nontemporal_load((const i32x4*)(p0 + 1028));
    i32x4 va3 = __builtin_nontemporal_load((const i32x4*)(p0 + 1536));
    i32x4 vb3 = __builtin_nontemporal_load((const i32x4*)(p0 + 1540));

    unsigned char* ob = bits + (size_t)c * 256 + lane;
    ob[0]   = (unsigned char)packbits(va0, vb0);
    ob[64]  = (unsigned char)packbits(va1, vb1);
    ob[128] = (unsigned char)packbits(va2, vb2);
    ob[192] = (unsigned char)packbits(va3, vb3);
  }
}

// ---------------- Phase 1: h = x@W (fp32), f1 = h@a1, f2 = h@a2, bpack = B-fragment layout ---
// bpack[jb][cb][lane=kgrp*16+r15][e] shorts: h[j = jb*32 + kgrp*8 + e][c = cb*16 + r15]
__global__ __launch_bounds__(256) void prep_kernel(
    const float* __restrict__ x, const float* __restrict__ W,
    const float* __restrict__ a, unsigned short* __restrict__ bpack,
    float* __restrict__ f1, float* __restrict__ f2) {
  const int lane = threadIdx.x & 63;
  const int g = blockIdx.x * 4 + (threadIdx.x >> 6);  // wave id 0..1023
  const int i0 = g * 8;

  float acc[8];
#pragma unroll
  for (int r = 0; r < 8; ++r) acc[r] = 0.0f;

  for (int k = 0; k < FIN; k += 4) {
    float w0 = W[(k + 0) * FOUT + lane];
    float w1 = W[(k + 1) * FOUT + lane];
    float w2 = W[(k + 2) * FOUT + lane];
    float w3 = W[(k + 3) * FOUT + lane];
#pragma unroll
    for (int r = 0; r < 8; ++r) {
      f32x4 xv = *(const f32x4*)(x + (size_t)(i0 + r) * FIN + k);
      acc[r] = fmaf(xv[0], w0, acc[r]);
      acc[r] = fmaf(xv[1], w1, acc[r]);
      acc[r] = fmaf(xv[2], w2, acc[r]);
      acc[r] = fmaf(xv[3], w3, acc[r]);
    }
  }

  const float a1c = a[lane];
  const float a2c = a[FOUT + lane];
#pragma unroll
  for (int r = 0; r < 8; ++r) {
    float p1 = acc[r] * a1c;
    float p2 = acc[r] * a2c;
#pragma unroll
    for (int off = 32; off >= 1; off >>= 1) {
      p1 += __shfl_xor(p1, off, 64);
      p2 += __shfl_xor(p2, off, 64);
    }
    if (lane == 0) { f1[i0 + r] = p1; f2[i0 + r] = p2; }
  }

  unsigned short hs[8];
#pragma unroll
  for (int r = 0; r < 8; ++r) hs[r] = f2bf(acc[r]);
  const int jb = i0 >> 5;
  const int kg = (i0 >> 3) & 3;
  const int cb = lane >> 4;
  const int rr = lane & 15;
  *(uint4*)(bpack + ((size_t)jb * 2048 + cb * 512 + kg * 128 + rr * 8)) = *(uint4*)hs;
}

// ---------------- Phase 2: fused GAT attention from bitmask (no HBM in the barrier loop) ----
// Block = 16 rows, 16 waves. Wave wv owns row wv (weights) and k-slice wv (MFMA).
__global__ __launch_bounds__(1024, 4) void attn_kernel(
    const unsigned char* __restrict__ bits, const unsigned short* __restrict__ bpack,
    const float* __restrict__ f1, const float* __restrict__ f2,
    float* __restrict__ out) {
  __shared__ __align__(16) char lds[16 * 16 * 64 * 4];  // 64 KB: pw dbuf (2x16KB) / num union
  __shared__ float lds_den[16];

  char* pwb0 = lds;            // pw buffer 0: [16 rows][512] bf16, swizzled
  char* pwb1 = lds + 16384;    // pw buffer 1
  float (*lds_num)[16][64] = (float (*)[16][64])lds;

  const int tid = threadIdx.x;
  const int lane = tid & 63;
  const int wv = tid >> 6;     // 0..15 : row owner AND k-slice owner
  const int rg = blockIdx.x;   // 0..511
  const int r15 = lane & 15;
  const int kgrp = lane >> 4;

  const int row_w = rg * 16 + wv;
  const float f1w = f1[row_w];
  const unsigned char* bitsrow = bits + (size_t)row_w * (NN / 8);

  // LDS addresses (bytes); lane owns j = lane*8..+7 of the tile on the write side
  int ard = r15 * 1024 + wv * 64 + kgrp * 16;
  ard ^= (r15 & 7) << 4;                       // swizzled A-frag read
  int awr = wv * 1024 + lane * 16;
  awr ^= (wv & 7) << 4;                        // swizzled weight write (16B per lane)

  f32x4 acc0 = {0.f, 0.f, 0.f, 0.f};
  f32x4 acc1 = acc0, acc2 = acc0, acc3 = acc0;
  float den = 0.0f;

  // prefetch tile 0 mask byte + f2
  unsigned bcur = bitsrow[lane];
  f32x4 fA = *(const f32x4*)(f2 + lane * 8);
  f32x4 fB = *(const f32x4*)(f2 + lane * 8 + 4);

  for (int t = 0; t < NT; ++t) {
    // issue this iter's bpack loads early (L2, covered by weight VALU below)
    const unsigned short* bp = bpack + ((size_t)(t * 16 + wv) * 2048 + lane * 8);
    bf16x8 b0 = *(const bf16x8*)(bp);
    bf16x8 b1 = *(const bf16x8*)(bp + 512);
    bf16x8 b2 = *(const bf16x8*)(bp + 1024);
    bf16x8 b3 = *(const bf16x8*)(bp + 1536);

    // issue next iter's mask/f2 loads (L1/L2)
    const int tn = (t + 1) & (NT - 1);
    unsigned bnxt = bitsrow[tn * 64 + lane];
    f32x4 nfA = *(const f32x4*)(f2 + tn * TJ + lane * 8);
    f32x4 nfB = *(const f32x4*)(f2 + tn * TJ + lane * 8 + 4);

    // weights for row wv, j = t*512 + lane*8 .. +7
    unsigned short ws8[8];
    float dsum = 0.0f;
#pragma unroll
    for (int e = 0; e < 4; ++e) {
      float s = f1w + fA[e];
      float l = fmaxf(s, ALPHA * s);
      float ev = __expf(l);
      float w_ = ((bcur >> e) & 1u) ? ev : 0.0f;
      dsum += w_;
      ws8[e] = f2bf(w_);
    }
#pragma unroll
    for (int e = 0; e < 4; ++e) {
      float s = f1w + fB[e];
      float l = fmaxf(s, ALPHA * s);
      float ev = __expf(l);
      float w_ = ((bcur >> (4 + e)) & 1u) ? ev : 0.0f;
      dsum += w_;
      ws8[4 + e] = f2bf(w_);
    }
    den += dsum;

    char* pwb = (t & 1) ? pwb1 : pwb0;
    *(uint4*)(pwb + awr) = *(uint4*)ws8;

    __syncthreads();   // pw visible; bpack/bits/f2 loads issued ~600cy ago -> drain is cheap

    // MFMA phase: this wave handles k-slice [t*512 + wv*32, +32)
    bf16x8 afrag = *(bf16x8*)(pwb + ard);
    acc0 = __builtin_amdgcn_mfma_f32_16x16x32_bf16(afrag, b0, acc0, 0, 0, 0);
    acc1 = __builtin_amdgcn_mfma_f32_16x16x32_bf16(afrag, b1, acc1, 0, 0, 0);
    acc2 = __builtin_amdgcn_mfma_f32_16x16x32_bf16(afrag, b2, acc2, 0, 0, 0);
    acc3 = __builtin_amdgcn_mfma_f32_16x16x32_bf16(afrag, b3, acc3, 0, 0, 0);

    bcur = bnxt; fA = nfA; fB = nfB;
  }

  // full-row denominator (wave wv owns row wv's entire j-range)
#pragma unroll
  for (int off = 1; off <= 32; off <<= 1) den += __shfl_xor(den, off, 64);

  __syncthreads();   // all pw reads done before aliasing lds as num

  // C layout: col = lane&15 (n), row = kgrp*4 + reg (m)
#pragma unroll
  for (int r = 0; r < 4; ++r) {
    lds_num[wv][kgrp * 4 + r][0 * 16 + r15] = acc0[r];
    lds_num[wv][kgrp * 4 + r][1 * 16 + r15] = acc1[r];
    lds_num[wv][kgrp * 4 + r][2 * 16 + r15] = acc2[r];
    lds_num[wv][kgrp * 4 + r][3 * 16 + r15] = acc3[r];
  }
  if (lane == 0) lds_den[wv] = den;
  __syncthreads();

  // combine 16 k-partials, divide, elu, store: one element per thread
  {
    const int orow = tid >> 6;
    const int ocol = tid & 63;
    float s = 0.0f;
#pragma unroll
    for (int v = 0; v < 16; ++v) s += lds_num[v][orow][ocol];
    float vv = s / lds_den[orow];
    out[(size_t)(rg * 16 + orow) * FOUT + ocol] = (vv > 0.0f) ? vv : (__expf(vv) - 1.0f);
  }
}

extern "C" void kernel_launch(void* const* d_in, const int* in_sizes, int n_in,
                              void* d_out, int out_size, void* d_ws, size_t ws_size,
                              hipStream_t stream) {
  const float* x = (const float*)d_in[0];
  const int* adj = (const int*)d_in[1];
  const float* W = (const float*)d_in[2];
  const float* a = (const float*)d_in[3];
  float* out = (float*)d_out;

  char* ws = (char*)d_ws;
  unsigned short* bpack = (unsigned short*)ws;                 // 1 MB
  float* f1 = (float*)(ws + (size_t)FOUT * NN * 2);            // 32 KB
  float* f2 = f1 + NN;                                         // 32 KB
  unsigned char* bits = (unsigned char*)(ws + (2u << 20));     // 8 MB at offset 2MB

  hipLaunchKernelGGL(prep_kernel, dim3(256), dim3(256), 0, stream, x, W, a, bpack, f1, f2);
  hipLaunchKernelGGL(compact_kernel, dim3(2048), dim3(256), 0, stream, adj, bits);
  hipLaunchKernelGGL(attn_kernel, dim3(512), dim3(1024), 0, stream, bits, bpack, f1, f2, out);
}